// Round 16
// baseline (222.530 us; speedup 1.0000x reference)
//
#include <hip/hip_runtime.h>
#include <math.h>
#include <stdint.h>

#define NB 16
#define SQ 1024
#define DD 1024

typedef _Float16 f16x8 __attribute__((ext_vector_type(8)));
typedef float f32x4 __attribute__((ext_vector_type(4)));

// ---------------- prep: special-token masks, lengths, temperatures ----------------
__global__ void prep_kernel(const int* __restrict__ ids_src, const int* __restrict__ ids_tgt,
                            float* __restrict__ add_src, float* __restrict__ add_tgt,
                            float* __restrict__ itau){
  int b = blockIdx.x;
  __shared__ int csrc, ctgt;
  if (threadIdx.x == 0){ csrc = 0; ctgt = 0; }
  __syncthreads();
  int ls = 0, lt = 0;
  for (int i = threadIdx.x; i < SQ; i += blockDim.x){
    int id = ids_src[b*SQ + i];
    bool sp = (id == 0) || (id == 101) || (id == 102);
    add_src[b*SQ + i] = sp ? -10000.0f : 0.0f;
    ls += sp ? 0 : 1;
    id = ids_tgt[b*SQ + i];
    sp = (id == 0) || (id == 101) || (id == 102);
    add_tgt[b*SQ + i] = sp ? -10000.0f : 0.0f;
    lt += sp ? 0 : 1;
  }
  atomicAdd(&csrc, ls);
  atomicAdd(&ctgt, lt);
  __syncthreads();
  if (threadIdx.x == 0){
    itau[b]      = 1.0f / sqrtf((float)csrc);   // 1/sqrt(len_src)
    itau[NB + b] = 1.0f / sqrtf((float)ctgt);   // 1/sqrt(len_tgt)
  }
}

// ---------------- direct-split GEMM: async gload_lds of RAW fp32 + split at fragment read ----
// Staging is the proven round-6 gload_lds structure (linear LDS dest, pre-swizzled global
// source, zero bank conflicts) but on raw fp32 -- no staging VALU, no ds_write, no vmcnt
// chain on the critical path. The hi/lo fp16 split happens at FRAGMENT READ: each pair of
// f32x4 LDS reads yields both ah and al. LDS = 2 bufs x (A,B) x 128x32 f32 = 64KB (2 blk/CU).
// Swizzle: global granule G <-> LDS granule G ^ (row&7) (involution, both sides; 16-lane
// read batches spread 8 granule positions x2 = free 2-way). Epilogue = round-12 validated
// stats partials with __expf. Lessons kept: no 2-deep reg prefetch (spills, r9/r11); no
// res array (spills, r9); no 8-phase graft (r7 -30%).
#define NKS 32   // 1024/32

typedef const uint32_t __attribute__((address_space(1))) gu32_t;
typedef uint32_t __attribute__((address_space(3))) su32_t;

__device__ __forceinline__ void gload16(const void* g, void* l){
  __builtin_amdgcn_global_load_lds((gu32_t*)g, (su32_t*)l, 16, 0, 0);
}

__global__ __launch_bounds__(256, 2)
void gemm_dsplit(const float* __restrict__ A, const float* __restrict__ Bm,
                 float* __restrict__ C,
                 const float* __restrict__ add_src, const float* __restrict__ add_tgt,
                 const float* __restrict__ itau,
                 float* __restrict__ rpart, float* __restrict__ cpart){
  __shared__ float lds[2][2][4096];   // [buf][plane A,B][row*32 + swz_granule*4]  = 64KB
  const int tid  = threadIdx.x;
  const int wave = tid >> 6;
  const int lane = tid & 63;

  // XCD-aware block swizzle (1024 blocks, 1024 % 8 == 0 -> bijective)
  int bid = blockIdx.x;
  int wg  = (bid & 7) * 128 + (bid >> 3);
  int b   = wg >> 6;
  int by  = (wg >> 3) & 7;
  int bx  = wg & 7;

  const float* Ab = A  + ((size_t)b*SQ + by*128) * DD;
  const float* Bb = Bm + ((size_t)b*SQ + bx*128) * DD;

  // staging: unit c covers LDS granule Gall = c*256 + tid (linear dest; 16B each).
  // Gall<1024 -> A plane, else B. r = G>>3, g_lds = G&7; source granule = g_lds ^ (r&7).
  const float* src[8];
  int dst[8];
  #pragma unroll
  for (int c = 0; c < 8; ++c){
    int Gall = c*256 + tid;
    int plane = Gall >> 10;
    int G = Gall & 1023;
    int r = G >> 3, g = G & 7;
    src[c] = (plane ? Bb : Ab) + (size_t)r*DD + ((g ^ (r & 7)) << 2);
    dst[c] = plane*4096 + G*4;     // float index within lds[bu]
  }
  auto STAGE = [&](int bu, int k0){
    #pragma unroll
    for (int c = 0; c < 8; ++c)
      gload16(src[c] + k0, &lds[bu][0][0] + dst[c]);
  };

  // fragment geometry: lane (hi=lane>>4, lr=lane&15) needs row (wm/wn + m*16 + lr),
  // K-elems [8*hi, 8*hi+8) = global granules {2hi, 2hi+1} -> LDS granules {gA, gA^1},
  // gA = (2hi) ^ (lr&7)   ((row&7) == (lr&7) since wm, m*16 are multiples of 8).
  const int lr  = lane & 15;
  const int hi  = lane >> 4;
  const int gA  = (2*hi) ^ (lr & 7);
  const int wm  = (wave >> 1) * 64;
  const int wn  = (wave & 1) * 64;
  const int aoff  = (wm + lr)*32 + gA*4;
  const int aoffX = (wm + lr)*32 + (gA^1)*4;
  const int boff  = (wn + lr)*32 + gA*4;
  const int boffX = (wn + lr)*32 + (gA^1)*4;

  f32x4 accm[4][4], accc[4][4];
  #pragma unroll
  for (int m = 0; m < 4; ++m)
    #pragma unroll
    for (int n = 0; n < 4; ++n){ accm[m][n] = (f32x4)0.0f; accc[m][n] = (f32x4)0.0f; }

  // split 8 consecutive f32 (lo4 = elems 0-3, hi4 = 4-7) into hi/lo f16x8
  auto SPLIT8 = [&](float4 lo4, float4 hi4, f16x8& h, f16x8& l){
    float e[8] = {lo4.x, lo4.y, lo4.z, lo4.w, hi4.x, hi4.y, hi4.z, hi4.w};
    #pragma unroll
    for (int jj = 0; jj < 8; ++jj){
      _Float16 hh = (_Float16)e[jj];
      h[jj] = hh;
      l[jj] = (_Float16)((e[jj] - (float)hh) * 4096.0f);
    }
  };

  STAGE(0, 0);
  __syncthreads();

  for (int t = 0; t < NKS; ++t){
    const int bu = t & 1;
    if (t + 1 < NKS) STAGE(bu ^ 1, (t+1)*32);   // async into the other buffer

    const float* LA = &lds[bu][0][0];
    const float* LB = &lds[bu][1][0];
    f16x8 ah[4], al[4], bh[4], bl[4];
    #pragma unroll
    for (int m = 0; m < 4; ++m){
      SPLIT8(*(const float4*)(LA + aoff  + m*512),
             *(const float4*)(LA + aoffX + m*512), ah[m], al[m]);
      SPLIT8(*(const float4*)(LB + boff  + m*512),
             *(const float4*)(LB + boffX + m*512), bh[m], bl[m]);
    }
    #pragma unroll
    for (int m = 0; m < 4; ++m)
      #pragma unroll
      for (int n = 0; n < 4; ++n){
        accm[m][n] = __builtin_amdgcn_mfma_f32_16x16x32_f16(ah[m], bh[n], accm[m][n], 0, 0, 0);
        accc[m][n] = __builtin_amdgcn_mfma_f32_16x16x32_f16(ah[m], bl[n], accc[m][n], 0, 0, 0);
        accc[m][n] = __builtin_amdgcn_mfma_f32_16x16x32_f16(al[m], bh[n], accc[m][n], 0, 0, 0);
      }
    __syncthreads();
  }

  // ---------------- epilogue (round-12 validated) ----------------
  // C/D layout col=lane&15, row=(lane>>4)*4+reg.  res(m,n,j) recomputed on the fly.
  const float inv = 1.0f / 4096.0f;
  const int r0 = (lane >> 4) * 4;
  const int c0 = lane & 15;

  float* Cb = C + ((size_t)b*SQ + by*128 + wm)*SQ + bx*128 + wn;
  #pragma unroll
  for (int m = 0; m < 4; ++m)
    #pragma unroll
    for (int n = 0; n < 4; ++n)
      #pragma unroll
      for (int j = 0; j < 4; ++j)
        Cb[(size_t)(m*16 + r0 + j)*SQ + n*16 + c0] = fmaf(accc[m][n][j], inv, accm[m][n][j]);

  const float its = itau[b];        // col temp 1/sqrt(len_src)
  const float itt = itau[NB + b];   // row temp 1/sqrt(len_tgt)
  float at4[4];
  #pragma unroll
  for (int n = 0; n < 4; ++n)
    at4[n] = add_tgt[b*SQ + bx*128 + wn + n*16 + c0];

  // ---- row partials (per m-group, lean temporaries) ----
  {
    size_t rb = ((size_t)(b*16 + bx*2 + (wave & 1)))*3*SQ + by*128 + wm;
    #pragma unroll
    for (int m = 0; m < 4; ++m){
      float mx[4], s1[4], s2[4];
      #pragma unroll
      for (int j = 0; j < 4; ++j){
        float v = -1e30f;
        #pragma unroll
        for (int n = 0; n < 4; ++n)
          v = fmaxf(v, fmaf(accc[m][n][j], inv, accm[m][n][j]) + at4[n]);
        #pragma unroll
        for (int o = 1; o < 16; o <<= 1) v = fmaxf(v, __shfl_xor(v, o));
        mx[j] = v;
      }
      #pragma unroll
      for (int j = 0; j < 4; ++j){
        float a = 0.f, c = 0.f;
        #pragma unroll
        for (int n = 0; n < 4; ++n){
          float d = fmaf(accc[m][n][j], inv, accm[m][n][j]) + at4[n] - mx[j];
          a += __expf(d);
          c += __expf(d * itt);
        }
        #pragma unroll
        for (int o = 1; o < 16; o <<= 1){ a += __shfl_xor(a, o); c += __shfl_xor(c, o); }
        s1[j] = a; s2[j] = c;
      }
      if ((lane & 15) == 0){
        #pragma unroll
        for (int j = 0; j < 4; ++j){
          int rr = m*16 + r0 + j;
          rpart[rb + rr]        = mx[j];
          rpart[rb + SQ + rr]   = s1[j];
          rpart[rb + 2*SQ + rr] = s2[j];
        }
      }
    }
  }

  // ---- col partials (per n, scalar temporaries) ----
  {
    float asv[4][4];
    #pragma unroll
    for (int m = 0; m < 4; ++m)
      #pragma unroll
      for (int j = 0; j < 4; ++j)
        asv[m][j] = add_src[b*SQ + by*128 + wm + m*16 + r0 + j];

    size_t cb2 = ((size_t)(b*16 + by*2 + (wave >> 1)))*3*SQ + bx*128 + wn;
    #pragma unroll
    for (int n = 0; n < 4; ++n){
      float mx = -1e30f;
      #pragma unroll
      for (int m = 0; m < 4; ++m)
        #pragma unroll
        for (int j = 0; j < 4; ++j)
          mx = fmaxf(mx, fmaf(accc[m][n][j], inv, accm[m][n][j]) + asv[m][j]);
      mx = fmaxf(mx, __shfl_xor(mx, 16));
      mx = fmaxf(mx, __shfl_xor(mx, 32));
      float s1 = 0.f, s2 = 0.f;
      #pragma unroll
      for (int m = 0; m < 4; ++m)
        #pragma unroll
        for (int j = 0; j < 4; ++j){
          float d = fmaf(accc[m][n][j], inv, accm[m][n][j]) + asv[m][j] - mx;
          s1 += __expf(d);
          s2 += __expf(d * its);
        }
      s1 += __shfl_xor(s1, 16); s1 += __shfl_xor(s1, 32);
      s2 += __shfl_xor(s2, 16); s2 += __shfl_xor(s2, 32);
      if (lane < 16){
        int cc = n*16 + c0;
        cpart[cb2 + cc]        = mx;
        cpart[cb2 + SQ + cc]   = s1;
        cpart[cb2 + 2*SQ + cc] = s2;
      }
    }
  }
}

// ---------------- merge 16-chunk partials -> global row/col stats ----------------
__global__ void merge_stats(const float* __restrict__ rpart, const float* __restrict__ cpart,
                            const float* __restrict__ itau,
                            float* __restrict__ Mr, float* __restrict__ S1r, float* __restrict__ S2r,
                            float* __restrict__ Mc, float* __restrict__ S1c, float* __restrict__ S2c){
  int idx = blockIdx.x*256 + threadIdx.x;   // b*SQ + pos
  int b = idx >> 10;
  int pos = idx & 1023;
  const float* P = blockIdx.y ? cpart : rpart;
  float it = blockIdx.y ? itau[b] : itau[NB + b];
  float M = -1e30f;
  #pragma unroll 4
  for (int ch = 0; ch < 16; ++ch)
    M = fmaxf(M, P[((size_t)(b*16 + ch))*3*SQ + pos]);
  float s1 = 0.f, s2 = 0.f;
  #pragma unroll 4
  for (int ch = 0; ch < 16; ++ch){
    size_t base = ((size_t)(b*16 + ch))*3*SQ + pos;
    float mm = P[base];
    s1 += P[base + SQ]   * __expf(mm - M);
    s2 += P[base + 2*SQ] * __expf((mm - M)*it);
  }
  if (blockIdx.y == 0){ Mr[idx] = M; S1r[idx] = s1; S2r[idx] = s2; }
  else                { Mc[idx] = M; S1c[idx] = s1; S2c[idx] = s2; }
}

// ---------------- fp32 fallback GEMM ----------------
__global__ __launch_bounds__(256)
void gemm_nt(const float* __restrict__ A, const float* __restrict__ Bm, float* __restrict__ C){
  __shared__ float As[32][132];
  __shared__ float Bs[32][132];
  const int b = blockIdx.z;
  const float* Ab = A  + ((size_t)b*SQ + blockIdx.y*128) * DD;
  const float* Bb = Bm + ((size_t)b*SQ + blockIdx.x*128) * DD;
  const int tid = threadIdx.x;
  const int lr = tid >> 3;
  const int lc = (tid & 7) << 2;
  const int tx = tid & 15;
  const int ty = tid >> 4;

  float acc[8][8];
  #pragma unroll
  for (int i = 0; i < 8; ++i)
    #pragma unroll
    for (int j = 0; j < 8; ++j) acc[i][j] = 0.0f;

  for (int k0 = 0; k0 < DD; k0 += 32){
    #pragma unroll
    for (int p = 0; p < 4; ++p){
      int row = p*32 + lr;
      float4 va = *(const float4*)(Ab + (size_t)row*DD + k0 + lc);
      float4 vb = *(const float4*)(Bb + (size_t)row*DD + k0 + lc);
      As[lc+0][row] = va.x; As[lc+1][row] = va.y; As[lc+2][row] = va.z; As[lc+3][row] = va.w;
      Bs[lc+0][row] = vb.x; Bs[lc+1][row] = vb.y; Bs[lc+2][row] = vb.z; Bs[lc+3][row] = vb.w;
    }
    __syncthreads();
    #pragma unroll
    for (int k = 0; k < 32; ++k){
      float a[8], bb[8];
      *(float4*)(a)    = *(const float4*)&As[k][ty*4];
      *(float4*)(a+4)  = *(const float4*)&As[k][64 + ty*4];
      *(float4*)(bb)   = *(const float4*)&Bs[k][tx*4];
      *(float4*)(bb+4) = *(const float4*)&Bs[k][64 + tx*4];
      #pragma unroll
      for (int i = 0; i < 8; ++i)
        #pragma unroll
        for (int j = 0; j < 8; ++j)
          acc[i][j] = fmaf(a[i], bb[j], acc[i][j]);
    }
    __syncthreads();
  }

  float* Cb = C + (size_t)b*SQ*SQ + (size_t)(blockIdx.y*128)*SQ + blockIdx.x*128;
  #pragma unroll
  for (int i = 0; i < 8; ++i){
    int r = (i < 4) ? (ty*4 + i) : (64 + ty*4 + (i-4));
    *(float4*)(Cb + (size_t)r*SQ + tx*4)      = make_float4(acc[i][0],acc[i][1],acc[i][2],acc[i][3]);
    *(float4*)(Cb + (size_t)r*SQ + 64 + tx*4) = make_float4(acc[i][4],acc[i][5],acc[i][6],acc[i][7]);
  }
}

// ---------------- fallback stats (used only if ws too small) ----------------
#define NCH 64
__global__ __launch_bounds__(256)
void stats_pass(const float* __restrict__ scores,
                const float* __restrict__ add_src, const float* __restrict__ add_tgt,
                const float* __restrict__ itau,
                float* __restrict__ Mr, float* __restrict__ S1r, float* __restrict__ S2r,
                float* __restrict__ part){
  __shared__ float redm[16][4];
  __shared__ float red1[16][4];
  __shared__ float red2[16][4];
  const int b  = blockIdx.x >> 6;
  const int ch = blockIdx.x & 63;
  const int tid = threadIdx.x;
  const int wv = tid >> 6;
  const int t0 = tid << 2;
  const float its = itau[b];
  const float itt = itau[NB + b];

  const float* p = scores + ((size_t)b*SQ + ch*16)*SQ + t0;
  float4 at4 = *(const float4*)(add_tgt + b*SQ + t0);

  float4 x[16];
  #pragma unroll
  for (int s = 0; s < 16; ++s) x[s] = *(const float4*)(p + (size_t)s*SQ);

  #pragma unroll
  for (int s = 0; s < 16; ++s){
    float m = fmaxf(fmaxf(x[s].x + at4.x, x[s].y + at4.y),
                    fmaxf(x[s].z + at4.z, x[s].w + at4.w));
    #pragma unroll
    for (int o = 32; o > 0; o >>= 1) m = fmaxf(m, __shfl_xor(m, o));
    if ((tid & 63) == 0) redm[s][wv] = m;
  }
  __syncthreads();
  float Mrow[16];
  #pragma unroll
  for (int s = 0; s < 16; ++s)
    Mrow[s] = fmaxf(fmaxf(redm[s][0], redm[s][1]), fmaxf(redm[s][2], redm[s][3]));

  #pragma unroll
  for (int s = 0; s < 16; ++s){
    float d0 = x[s].x + at4.x - Mrow[s];
    float d1 = x[s].y + at4.y - Mrow[s];
    float d2 = x[s].z + at4.z - Mrow[s];
    float d3 = x[s].w + at4.w - Mrow[s];
    float s1 = expf(d0) + expf(d1) + expf(d2) + expf(d3);
    float s2 = expf(d0*itt) + expf(d1*itt) + expf(d2*itt) + expf(d3*itt);
    #pragma unroll
    for (int o = 32; o > 0; o >>= 1){ s1 += __shfl_xor(s1, o); s2 += __shfl_xor(s2, o); }
    if ((tid & 63) == 0){ red1[s][wv] = s1; red2[s][wv] = s2; }
  }
  __syncthreads();
  if (tid < 16){
    int s = tid;
    int row = b*SQ + ch*16 + s;
    Mr[row]  = fmaxf(fmaxf(redm[s][0], redm[s][1]), fmaxf(redm[s][2], redm[s][3]));
    S1r[row] = red1[s][0] + red1[s][1] + red1[s][2] + red1[s][3];
    S2r[row] = red2[s][0] + red2[s][1] + red2[s][2] + red2[s][3];
  }

  float asv[16];
  #pragma unroll
  for (int s = 0; s < 16; ++s) asv[s] = add_src[b*SQ + ch*16 + s];

  float cm0 = -1e30f, cm1 = -1e30f, cm2 = -1e30f, cm3 = -1e30f;
  #pragma unroll
  for (int s = 0; s < 16; ++s){
    cm0 = fmaxf(cm0, x[s].x + asv[s]);
    cm1 = fmaxf(cm1, x[s].y + asv[s]);
    cm2 = fmaxf(cm2, x[s].z + asv[s]);
    cm3 = fmaxf(cm3, x[s].w + asv[s]);
  }
  float c10 = 0.f, c11 = 0.f, c12 = 0.f, c13 = 0.f;
  float c20 = 0.f, c21 = 0.f, c22 = 0.f, c23 = 0.f;
  #pragma unroll
  for (int s = 0; s < 16; ++s){
    float d0 = x[s].x + asv[s] - cm0;
    float d1 = x[s].y + asv[s] - cm1;
    float d2 = x[s].z + asv[s] - cm2;
    float d3 = x[s].w + asv[s] - cm3;
    c10 += expf(d0); c11 += expf(d1); c12 += expf(d2); c13 += expf(d3);
    c20 += expf(d0*its); c21 += expf(d1*its); c22 += expf(d2*its); c23 += expf(d3*its);
  }
  size_t base = (size_t)blockIdx.x * 3 * SQ + t0;
  *(float4*)(part + base)        = make_float4(cm0, cm1, cm2, cm3);
  *(float4*)(part + base + SQ)   = make_float4(c10, c11, c12, c13);
  *(float4*)(part + base + 2*SQ) = make_float4(c20, c21, c22, c23);
}

__global__ void col_merge(const float* __restrict__ part, const float* __restrict__ itau,
                          float* __restrict__ Mc, float* __restrict__ S1c, float* __restrict__ S2c){
  int idx = blockIdx.x*256 + threadIdx.x;
  int b = idx >> 10;
  int t = idx & 1023;
  float it = itau[b];
  float M = -1e30f;
  for (int ch = 0; ch < NCH; ++ch)
    M = fmaxf(M, part[(size_t)(b*NCH+ch)*3*SQ + t]);
  float s1 = 0.f, s2 = 0.f;
  for (int ch = 0; ch < NCH; ++ch){
    size_t base = (size_t)(b*NCH+ch)*3*SQ + t;
    float mm = part[base];
    s1 += part[base +   SQ] * expf(mm - M);
    s2 += part[base + 2*SQ] * expf((mm - M)*it);
  }
  Mc[idx] = M; S1c[idx] = s1; S2c[idx] = s2;
}

// ---------------- finalize ----------------
__global__ __launch_bounds__(256)
void finalize(const float* __restrict__ scores,
              const float* __restrict__ add_src, const float* __restrict__ add_tgt,
              const float* __restrict__ itau,
              const float* __restrict__ Mr, const float* __restrict__ S1r, const float* __restrict__ S2r,
              const float* __restrict__ Mc, const float* __restrict__ S1c, const float* __restrict__ S2c,
              float* __restrict__ out0, float* __restrict__ out1){
  int row = blockIdx.x;
  int b = row >> 10;
  float Mrv = Mr[row], s1r = S1r[row], s2r = S2r[row];
  float ads = add_src[row];
  float itt = itau[NB + b], its = itau[b];
  int t = threadIdx.x << 2;
  size_t off = (size_t)row*SQ + t;
  float4 x4  = *(const float4*)(scores + off);
  int bt = b*SQ + t;
  float4 at4 = *(const float4*)(add_tgt + bt);
  float4 mc4 = *(const float4*)(Mc  + bt);
  float4 c14 = *(const float4*)(S1c + bt);
  float4 c24 = *(const float4*)(S2c + bt);
  const float* xp  = (const float*)&x4;
  const float* atp = (const float*)&at4;
  const float* mcp = (const float*)&mc4;
  const float* c1p = (const float*)&c14;
  const float* c2p = (const float*)&c24;
  float o0[4], o1[4];
  #pragma unroll
  for (int j = 0; j < 4; ++j){
    float x  = xp[j];
    float xs = x + atp[j];
    float ps = __expf(xs - Mrv) / s1r;
    float qs = __expf((xs - Mrv)*itt) / s2r;
    float xt = x + ads;
    float pt = __expf(xt - mcp[j]) / c1p[j];
    float qt = __expf((xt - mcp[j])*its) / c2p[j];
    o0[j] = (ps > 1e-3f && pt > 1e-3f) ? 1.0f : 0.0f;
    o1[j] = 2.0f*qs*qt / (qs + qt + 1e-9f);
  }
  *(float4*)(out0 + off) = make_float4(o0[0],o0[1],o0[2],o0[3]);
  *(float4*)(out1 + off) = make_float4(o1[0],o1[1],o1[2],o1[3]);
}

extern "C" void kernel_launch(void* const* d_in, const int* in_sizes, int n_in,
                              void* d_out, int out_size, void* d_ws, size_t ws_size,
                              hipStream_t stream){
  const float* hsrc = (const float*)d_in[0];
  const float* htgt = (const float*)d_in[1];
  const int*   isrc = (const int*)d_in[2];
  const int*   itgt = (const int*)d_in[3];

  float* out0 = (float*)d_out;
  float* out1 = out0 + (size_t)NB*SQ*SQ;
  float* W = (float*)d_ws;

  const size_t NSQ2 = (size_t)NB*SQ*SQ;              // 16,777,216
  const size_t need_fast = (NSQ2 + 16384*2 + 32 + 6*NB*SQ + 2*(size_t)NB*16*3*SQ) * 4;

  if (ws_size >= need_fast){
    float* scores  = W;                         // 16M floats
    float* add_src = W + NSQ2;
    float* add_tgt = add_src + NB*SQ;
    float* itau    = add_tgt + NB*SQ;
    float* Mr      = itau + 32;
    float* S1r     = Mr  + NB*SQ;
    float* S2r     = S1r + NB*SQ;
    float* Mc      = S2r + NB*SQ;
    float* S1c     = Mc  + NB*SQ;
    float* S2c     = S1c + NB*SQ;
    float* rpart   = S2c + NB*SQ;               // NB*16*3*SQ = 786,432 floats
    float* cpart   = rpart + (size_t)NB*16*3*SQ;

    prep_kernel<<<NB, 256, 0, stream>>>(isrc, itgt, add_src, add_tgt, itau);
    gemm_dsplit<<<1024, 256, 0, stream>>>(hsrc, htgt, scores, add_src, add_tgt, itau,
                                          rpart, cpart);
    merge_stats<<<dim3(NB*SQ/256, 2), 256, 0, stream>>>(rpart, cpart, itau,
                                                        Mr, S1r, S2r, Mc, S1c, S2c);
    finalize<<<NB*SQ, 256, 0, stream>>>(scores, add_src, add_tgt, itau,
                                        Mr, S1r, S2r, Mc, S1c, S2c, out0, out1);
  } else {
    // fallback: fp32 GEMM path, scores staged in out1 (finalize overwrites in place)
    float* scores  = out1;
    float* add_src = W;
    float* add_tgt = W + 16384;
    float* itau    = W + 32768;
    float* Mr      = W + 32800;
    float* S1r     = Mr  + NB*SQ;
    float* S2r     = S1r + NB*SQ;
    float* Mc      = S2r + NB*SQ;
    float* S1c     = Mc  + NB*SQ;
    float* S2c     = S1c + NB*SQ;
    float* part    = S2c + NB*SQ;

    prep_kernel<<<NB, 256, 0, stream>>>(isrc, itgt, add_src, add_tgt, itau);
    gemm_nt<<<dim3(8, 8, NB), 256, 0, stream>>>(hsrc, htgt, scores);
    stats_pass<<<NB*NCH, 256, 0, stream>>>(scores, add_src, add_tgt, itau, Mr, S1r, S2r, part);
    col_merge<<<NB*SQ/256, 256, 0, stream>>>(part, itau, Mc, S1c, S2c);
    finalize<<<NB*SQ, 256, 0, stream>>>(scores, add_src, add_tgt, itau,
                                        Mr, S1r, S2r, Mc, S1c, S2c, out0, out1);
  }
}

// Round 18
// 195.139 us; speedup vs baseline: 1.1404x; 1.1404x over previous
//
#include <hip/hip_runtime.h>
#include <math.h>
#include <stdint.h>

#define NB 16
#define SQ 1024
#define DD 1024

typedef _Float16 f16x8 __attribute__((ext_vector_type(8)));
typedef float f32x4 __attribute__((ext_vector_type(4)));

// ---------------- prep: special-token masks, lengths, temperatures ----------------
__global__ void prep_kernel(const int* __restrict__ ids_src, const int* __restrict__ ids_tgt,
                            float* __restrict__ add_src, float* __restrict__ add_tgt,
                            float* __restrict__ itau){
  int b = blockIdx.x;
  __shared__ int csrc, ctgt;
  if (threadIdx.x == 0){ csrc = 0; ctgt = 0; }
  __syncthreads();
  int ls = 0, lt = 0;
  for (int i = threadIdx.x; i < SQ; i += blockDim.x){
    int id = ids_src[b*SQ + i];
    bool sp = (id == 0) || (id == 101) || (id == 102);
    add_src[b*SQ + i] = sp ? -10000.0f : 0.0f;
    ls += sp ? 0 : 1;
    id = ids_tgt[b*SQ + i];
    sp = (id == 0) || (id == 101) || (id == 102);
    add_tgt[b*SQ + i] = sp ? -10000.0f : 0.0f;
    lt += sp ? 0 : 1;
  }
  atomicAdd(&csrc, ls);
  atomicAdd(&ctgt, lt);
  __syncthreads();
  if (threadIdx.x == 0){
    itau[b]      = 1.0f / sqrtf((float)csrc);   // 1/sqrt(len_src)
    itau[NB + b] = 1.0f / sqrtf((float)ctgt);   // 1/sqrt(len_tgt)
  }
}

// ---------------- fused-split fp16 MFMA GEMM + lean in-epilogue softmax partials ----------------
// Round-12 structure (best: 196us total, no spills at VGPR 112 + 128 AGPR, 2 blocks/CU):
// 1-deep register staging, in-register hi/lo fp16 split, swizzled ds_write/ds_read_b128
// (swz(row)=(row>>1)&3, conflict-free), double-buffered 64KB LDS, lean __expf epilogue.
// ONE change vs round 12: split uses packed v_cvt_pkrtz_f16_f32 (fewer ops/elem) --
// RTZ hi is safe since lo is computed from the converted-back hi (residual exact).
// LESSONS (do not undo): no 2-deep reg prefetch (r9/r11 spill: WRITE_SIZE ~200MB);
// no res[4][4][4] array (r9 spill); no 8-phase graft (r7 -30%); no MFMA/WRITE hand
// interleave (r15 neutral-to-worse); no fp32-in-LDS split-at-read (r16: conflicts + 2x VALU).
#define NKS 32   // 1024/32

__global__ __launch_bounds__(256, 2)
void gemm_fsplit(const float* __restrict__ A, const float* __restrict__ Bm,
                 float* __restrict__ C,
                 const float* __restrict__ add_src, const float* __restrict__ add_tgt,
                 const float* __restrict__ itau,
                 float* __restrict__ rpart, float* __restrict__ cpart){
  __shared__ _Float16 lds[2][4][128*32];   // [buf][plane: Ahi,Alo,Bhi,Blo][row*32 + swz slot*8]
  const int tid  = threadIdx.x;
  const int wave = tid >> 6;
  const int lane = tid & 63;

  // XCD-aware block swizzle (1024 blocks, 1024 % 8 == 0 -> bijective)
  int bid = blockIdx.x;
  int wg  = (bid & 7) * 128 + (bid >> 3);
  int b   = wg >> 6;
  int by  = (wg >> 3) & 7;
  int bx  = wg & 7;

  const float* Ab = A  + ((size_t)b*SQ + by*128) * DD;
  const float* Bb = Bm + ((size_t)b*SQ + bx*128) * DD;

  // staging assignment: thread covers rows {sr, sr+64} of A and B, k-slot ss (8 floats)
  const int sr = tid >> 2;        // 0..63
  const int ss = tid & 3;         // k-slot
  const int wsl = ss ^ ((sr >> 1) & 3);          // swizzled slot
  const int w0 = (sr      *4 + wsl)*8;
  const int w1 = ((sr+64) *4 + wsl)*8;

  float4 rg[4][2];   // 4 units x 8 floats
  auto LOADR = [&](int k0){
    const float* pa0 = Ab + (size_t)sr*DD      + k0 + ss*8;
    const float* pa1 = Ab + (size_t)(sr+64)*DD + k0 + ss*8;
    const float* pb0 = Bb + (size_t)sr*DD      + k0 + ss*8;
    const float* pb1 = Bb + (size_t)(sr+64)*DD + k0 + ss*8;
    rg[0][0] = *(const float4*)pa0; rg[0][1] = *(const float4*)(pa0+4);
    rg[1][0] = *(const float4*)pa1; rg[1][1] = *(const float4*)(pa1+4);
    rg[2][0] = *(const float4*)pb0; rg[2][1] = *(const float4*)(pb0+4);
    rg[3][0] = *(const float4*)pb1; rg[3][1] = *(const float4*)(pb1+4);
  };
  auto WRITE = [&](int bu){
    #pragma unroll
    for (int u = 0; u < 4; ++u){
      const float* v = (const float*)&rg[u][0];
      f16x8 h, l;
      #pragma unroll
      for (int p = 0; p < 4; ++p){
        float x0 = v[2*p], x1 = v[2*p+1];
        auto hp = __builtin_amdgcn_cvt_pkrtz(x0, x1);             // packed RTZ hi (__fp16x2)
        float h0 = (float)hp[0], h1 = (float)hp[1];
        auto lp = __builtin_amdgcn_cvt_pkrtz((x0 - h0)*4096.0f,   // packed lo (exact residual)
                                             (x1 - h1)*4096.0f);
        h[2*p] = (_Float16)hp[0]; h[2*p+1] = (_Float16)hp[1];
        l[2*p] = (_Float16)lp[0]; l[2*p+1] = (_Float16)lp[1];
      }
      const int hp_ = (u < 2) ? 0 : 2;
      const int wo  = (u & 1) ? w1 : w0;
      *(f16x8*)&lds[bu][hp_  ][wo] = h;
      *(f16x8*)&lds[bu][hp_+1][wo] = l;
    }
  };

  // fragment read offsets (fp16 elems): row*32 + swizzled_slot*8
  const int lr  = lane & 15;
  const int ls8 = (((lane >> 4) ^ ((lr >> 1) & 3)) << 3);
  const int wm  = (wave >> 1) * 64;
  const int wn  = (wave & 1) * 64;
  const int aoffL = (wm + lr)*32 + ls8;
  const int boffL = (wn + lr)*32 + ls8;

  f32x4 accm[4][4], accc[4][4];
  #pragma unroll
  for (int m = 0; m < 4; ++m)
    #pragma unroll
    for (int n = 0; n < 4; ++n){ accm[m][n] = (f32x4)0.0f; accc[m][n] = (f32x4)0.0f; }

  // prologue: stage tile 0 into buf 0
  LOADR(0);
  WRITE(0);
  __syncthreads();

  for (int t = 0; t < NKS; ++t){
    const int bu = t & 1;
    if (t + 1 < NKS) LOADR((t+1)*32);

    f16x8 ah[4], al[4], bh[4], bl[4];
    #pragma unroll
    for (int m = 0; m < 4; ++m){
      ah[m] = *(const f16x8*)&lds[bu][0][aoffL + m*512];
      al[m] = *(const f16x8*)&lds[bu][1][aoffL + m*512];
      bh[m] = *(const f16x8*)&lds[bu][2][boffL + m*512];
      bl[m] = *(const f16x8*)&lds[bu][3][boffL + m*512];
    }
    #pragma unroll
    for (int m = 0; m < 4; ++m)
      #pragma unroll
      for (int n = 0; n < 4; ++n){
        accm[m][n] = __builtin_amdgcn_mfma_f32_16x16x32_f16(ah[m], bh[n], accm[m][n], 0, 0, 0);
        accc[m][n] = __builtin_amdgcn_mfma_f32_16x16x32_f16(ah[m], bl[n], accc[m][n], 0, 0, 0);
        accc[m][n] = __builtin_amdgcn_mfma_f32_16x16x32_f16(al[m], bh[n], accc[m][n], 0, 0, 0);
      }

    if (t + 1 < NKS) WRITE(bu ^ 1);
    __syncthreads();
  }

  // ---------------- epilogue ----------------
  // C/D layout col=lane&15, row=(lane>>4)*4+reg.  res(m,n,j) recomputed on the fly.
  const float inv = 1.0f / 4096.0f;
  const int r0 = (lane >> 4) * 4;
  const int c0 = lane & 15;

  // C write straight from acc (stores drain under the stats VALU work below)
  float* Cb = C + ((size_t)b*SQ + by*128 + wm)*SQ + bx*128 + wn;
  #pragma unroll
  for (int m = 0; m < 4; ++m)
    #pragma unroll
    for (int n = 0; n < 4; ++n)
      #pragma unroll
      for (int j = 0; j < 4; ++j)
        Cb[(size_t)(m*16 + r0 + j)*SQ + n*16 + c0] = fmaf(accc[m][n][j], inv, accm[m][n][j]);

  const float its = itau[b];        // col temp 1/sqrt(len_src)
  const float itt = itau[NB + b];   // row temp 1/sqrt(len_tgt)
  float at4[4];
  #pragma unroll
  for (int n = 0; n < 4; ++n)
    at4[n] = add_tgt[b*SQ + bx*128 + wn + n*16 + c0];

  // ---- row partials (per m-group, lean temporaries) ----
  {
    size_t rb = ((size_t)(b*16 + bx*2 + (wave & 1)))*3*SQ + by*128 + wm;
    #pragma unroll
    for (int m = 0; m < 4; ++m){
      float mx[4], s1[4], s2[4];
      #pragma unroll
      for (int j = 0; j < 4; ++j){
        float v = -1e30f;
        #pragma unroll
        for (int n = 0; n < 4; ++n)
          v = fmaxf(v, fmaf(accc[m][n][j], inv, accm[m][n][j]) + at4[n]);
        #pragma unroll
        for (int o = 1; o < 16; o <<= 1) v = fmaxf(v, __shfl_xor(v, o));
        mx[j] = v;
      }
      #pragma unroll
      for (int j = 0; j < 4; ++j){
        float a = 0.f, c = 0.f;
        #pragma unroll
        for (int n = 0; n < 4; ++n){
          float d = fmaf(accc[m][n][j], inv, accm[m][n][j]) + at4[n] - mx[j];
          a += __expf(d);
          c += __expf(d * itt);
        }
        #pragma unroll
        for (int o = 1; o < 16; o <<= 1){ a += __shfl_xor(a, o); c += __shfl_xor(c, o); }
        s1[j] = a; s2[j] = c;
      }
      if ((lane & 15) == 0){
        #pragma unroll
        for (int j = 0; j < 4; ++j){
          int rr = m*16 + r0 + j;
          rpart[rb + rr]        = mx[j];
          rpart[rb + SQ + rr]   = s1[j];
          rpart[rb + 2*SQ + rr] = s2[j];
        }
      }
    }
  }

  // ---- col partials (per n, scalar temporaries) ----
  {
    float asv[4][4];
    #pragma unroll
    for (int m = 0; m < 4; ++m)
      #pragma unroll
      for (int j = 0; j < 4; ++j)
        asv[m][j] = add_src[b*SQ + by*128 + wm + m*16 + r0 + j];

    size_t cb2 = ((size_t)(b*16 + by*2 + (wave >> 1)))*3*SQ + bx*128 + wn;
    #pragma unroll
    for (int n = 0; n < 4; ++n){
      float mx = -1e30f;
      #pragma unroll
      for (int m = 0; m < 4; ++m)
        #pragma unroll
        for (int j = 0; j < 4; ++j)
          mx = fmaxf(mx, fmaf(accc[m][n][j], inv, accm[m][n][j]) + asv[m][j]);
      mx = fmaxf(mx, __shfl_xor(mx, 16));
      mx = fmaxf(mx, __shfl_xor(mx, 32));
      float s1 = 0.f, s2 = 0.f;
      #pragma unroll
      for (int m = 0; m < 4; ++m)
        #pragma unroll
        for (int j = 0; j < 4; ++j){
          float d = fmaf(accc[m][n][j], inv, accm[m][n][j]) + asv[m][j] - mx;
          s1 += __expf(d);
          s2 += __expf(d * its);
        }
      s1 += __shfl_xor(s1, 16); s1 += __shfl_xor(s1, 32);
      s2 += __shfl_xor(s2, 16); s2 += __shfl_xor(s2, 32);
      if (lane < 16){
        int cc = n*16 + c0;
        cpart[cb2 + cc]        = mx;
        cpart[cb2 + SQ + cc]   = s1;
        cpart[cb2 + 2*SQ + cc] = s2;
      }
    }
  }
}

// ---------------- merge 16-chunk partials -> global row/col stats ----------------
__global__ void merge_stats(const float* __restrict__ rpart, const float* __restrict__ cpart,
                            const float* __restrict__ itau,
                            float* __restrict__ Mr, float* __restrict__ S1r, float* __restrict__ S2r,
                            float* __restrict__ Mc, float* __restrict__ S1c, float* __restrict__ S2c){
  int idx = blockIdx.x*256 + threadIdx.x;   // b*SQ + pos
  int b = idx >> 10;
  int pos = idx & 1023;
  const float* P = blockIdx.y ? cpart : rpart;
  float it = blockIdx.y ? itau[b] : itau[NB + b];
  float M = -1e30f;
  #pragma unroll 4
  for (int ch = 0; ch < 16; ++ch)
    M = fmaxf(M, P[((size_t)(b*16 + ch))*3*SQ + pos]);
  float s1 = 0.f, s2 = 0.f;
  #pragma unroll 4
  for (int ch = 0; ch < 16; ++ch){
    size_t base = ((size_t)(b*16 + ch))*3*SQ + pos;
    float mm = P[base];
    s1 += P[base + SQ]   * __expf(mm - M);
    s2 += P[base + 2*SQ] * __expf((mm - M)*it);
  }
  if (blockIdx.y == 0){ Mr[idx] = M; S1r[idx] = s1; S2r[idx] = s2; }
  else                { Mc[idx] = M; S1c[idx] = s1; S2c[idx] = s2; }
}

// ---------------- fp32 fallback GEMM ----------------
__global__ __launch_bounds__(256)
void gemm_nt(const float* __restrict__ A, const float* __restrict__ Bm, float* __restrict__ C){
  __shared__ float As[32][132];
  __shared__ float Bs[32][132];
  const int b = blockIdx.z;
  const float* Ab = A  + ((size_t)b*SQ + blockIdx.y*128) * DD;
  const float* Bb = Bm + ((size_t)b*SQ + blockIdx.x*128) * DD;
  const int tid = threadIdx.x;
  const int lr = tid >> 3;
  const int lc = (tid & 7) << 2;
  const int tx = tid & 15;
  const int ty = tid >> 4;

  float acc[8][8];
  #pragma unroll
  for (int i = 0; i < 8; ++i)
    #pragma unroll
    for (int j = 0; j < 8; ++j) acc[i][j] = 0.0f;

  for (int k0 = 0; k0 < DD; k0 += 32){
    #pragma unroll
    for (int p = 0; p < 4; ++p){
      int row = p*32 + lr;
      float4 va = *(const float4*)(Ab + (size_t)row*DD + k0 + lc);
      float4 vb = *(const float4*)(Bb + (size_t)row*DD + k0 + lc);
      As[lc+0][row] = va.x; As[lc+1][row] = va.y; As[lc+2][row] = va.z; As[lc+3][row] = va.w;
      Bs[lc+0][row] = vb.x; Bs[lc+1][row] = vb.y; Bs[lc+2][row] = vb.z; Bs[lc+3][row] = vb.w;
    }
    __syncthreads();
    #pragma unroll
    for (int k = 0; k < 32; ++k){
      float a[8], bb[8];
      *(float4*)(a)    = *(const float4*)&As[k][ty*4];
      *(float4*)(a+4)  = *(const float4*)&As[k][64 + ty*4];
      *(float4*)(bb)   = *(const float4*)&Bs[k][tx*4];
      *(float4*)(bb+4) = *(const float4*)&Bs[k][64 + tx*4];
      #pragma unroll
      for (int i = 0; i < 8; ++i)
        #pragma unroll
        for (int j = 0; j < 8; ++j)
          acc[i][j] = fmaf(a[i], bb[j], acc[i][j]);
    }
    __syncthreads();
  }

  float* Cb = C + (size_t)b*SQ*SQ + (size_t)(blockIdx.y*128)*SQ + blockIdx.x*128;
  #pragma unroll
  for (int i = 0; i < 8; ++i){
    int r = (i < 4) ? (ty*4 + i) : (64 + ty*4 + (i-4));
    *(float4*)(Cb + (size_t)r*SQ + tx*4)      = make_float4(acc[i][0],acc[i][1],acc[i][2],acc[i][3]);
    *(float4*)(Cb + (size_t)r*SQ + 64 + tx*4) = make_float4(acc[i][4],acc[i][5],acc[i][6],acc[i][7]);
  }
}

// ---------------- fallback stats (used only if ws too small) ----------------
#define NCH 64
__global__ __launch_bounds__(256)
void stats_pass(const float* __restrict__ scores,
                const float* __restrict__ add_src, const float* __restrict__ add_tgt,
                const float* __restrict__ itau,
                float* __restrict__ Mr, float* __restrict__ S1r, float* __restrict__ S2r,
                float* __restrict__ part){
  __shared__ float redm[16][4];
  __shared__ float red1[16][4];
  __shared__ float red2[16][4];
  const int b  = blockIdx.x >> 6;
  const int ch = blockIdx.x & 63;
  const int tid = threadIdx.x;
  const int wv = tid >> 6;
  const int t0 = tid << 2;
  const float its = itau[b];
  const float itt = itau[NB + b];

  const float* p = scores + ((size_t)b*SQ + ch*16)*SQ + t0;
  float4 at4 = *(const float4*)(add_tgt + b*SQ + t0);

  float4 x[16];
  #pragma unroll
  for (int s = 0; s < 16; ++s) x[s] = *(const float4*)(p + (size_t)s*SQ);

  #pragma unroll
  for (int s = 0; s < 16; ++s){
    float m = fmaxf(fmaxf(x[s].x + at4.x, x[s].y + at4.y),
                    fmaxf(x[s].z + at4.z, x[s].w + at4.w));
    #pragma unroll
    for (int o = 32; o > 0; o >>= 1) m = fmaxf(m, __shfl_xor(m, o));
    if ((tid & 63) == 0) redm[s][wv] = m;
  }
  __syncthreads();
  float Mrow[16];
  #pragma unroll
  for (int s = 0; s < 16; ++s)
    Mrow[s] = fmaxf(fmaxf(redm[s][0], redm[s][1]), fmaxf(redm[s][2], redm[s][3]));

  #pragma unroll
  for (int s = 0; s < 16; ++s){
    float d0 = x[s].x + at4.x - Mrow[s];
    float d1 = x[s].y + at4.y - Mrow[s];
    float d2 = x[s].z + at4.z - Mrow[s];
    float d3 = x[s].w + at4.w - Mrow[s];
    float s1 = expf(d0) + expf(d1) + expf(d2) + expf(d3);
    float s2 = expf(d0*itt) + expf(d1*itt) + expf(d2*itt) + expf(d3*itt);
    #pragma unroll
    for (int o = 32; o > 0; o >>= 1){ s1 += __shfl_xor(s1, o); s2 += __shfl_xor(s2, o); }
    if ((tid & 63) == 0){ red1[s][wv] = s1; red2[s][wv] = s2; }
  }
  __syncthreads();
  if (tid < 16){
    int s = tid;
    int row = b*SQ + ch*16 + s;
    Mr[row]  = fmaxf(fmaxf(redm[s][0], redm[s][1]), fmaxf(redm[s][2], redm[s][3]));
    S1r[row] = red1[s][0] + red1[s][1] + red1[s][2] + red1[s][3];
    S2r[row] = red2[s][0] + red2[s][1] + red2[s][2] + red2[s][3];
  }

  float asv[16];
  #pragma unroll
  for (int s = 0; s < 16; ++s) asv[s] = add_src[b*SQ + ch*16 + s];

  float cm0 = -1e30f, cm1 = -1e30f, cm2 = -1e30f, cm3 = -1e30f;
  #pragma unroll
  for (int s = 0; s < 16; ++s){
    cm0 = fmaxf(cm0, x[s].x + asv[s]);
    cm1 = fmaxf(cm1, x[s].y + asv[s]);
    cm2 = fmaxf(cm2, x[s].z + asv[s]);
    cm3 = fmaxf(cm3, x[s].w + asv[s]);
  }
  float c10 = 0.f, c11 = 0.f, c12 = 0.f, c13 = 0.f;
  float c20 = 0.f, c21 = 0.f, c22 = 0.f, c23 = 0.f;
  #pragma unroll
  for (int s = 0; s < 16; ++s){
    float d0 = x[s].x + asv[s] - cm0;
    float d1 = x[s].y + asv[s] - cm1;
    float d2 = x[s].z + asv[s] - cm2;
    float d3 = x[s].w + asv[s] - cm3;
    c10 += expf(d0); c11 += expf(d1); c12 += expf(d2); c13 += expf(d3);
    c20 += expf(d0*its); c21 += expf(d1*its); c22 += expf(d2*its); c23 += expf(d3*its);
  }
  size_t base = (size_t)blockIdx.x * 3 * SQ + t0;
  *(float4*)(part + base)        = make_float4(cm0, cm1, cm2, cm3);
  *(float4*)(part + base + SQ)   = make_float4(c10, c11, c12, c13);
  *(float4*)(part + base + 2*SQ) = make_float4(c20, c21, c22, c23);
}

__global__ void col_merge(const float* __restrict__ part, const float* __restrict__ itau,
                          float* __restrict__ Mc, float* __restrict__ S1c, float* __restrict__ S2c){
  int idx = blockIdx.x*256 + threadIdx.x;
  int b = idx >> 10;
  int t = idx & 1023;
  float it = itau[b];
  float M = -1e30f;
  for (int ch = 0; ch < NCH; ++ch)
    M = fmaxf(M, part[(size_t)(b*NCH+ch)*3*SQ + t]);
  float s1 = 0.f, s2 = 0.f;
  for (int ch = 0; ch < NCH; ++ch){
    size_t base = (size_t)(b*NCH+ch)*3*SQ + t;
    float mm = part[base];
    s1 += part[base +   SQ] * expf(mm - M);
    s2 += part[base + 2*SQ] * expf((mm - M)*it);
  }
  Mc[idx] = M; S1c[idx] = s1; S2c[idx] = s2;
}

// ---------------- finalize ----------------
__global__ __launch_bounds__(256)
void finalize(const float* __restrict__ scores,
              const float* __restrict__ add_src, const float* __restrict__ add_tgt,
              const float* __restrict__ itau,
              const float* __restrict__ Mr, const float* __restrict__ S1r, const float* __restrict__ S2r,
              const float* __restrict__ Mc, const float* __restrict__ S1c, const float* __restrict__ S2c,
              float* __restrict__ out0, float* __restrict__ out1){
  int row = blockIdx.x;
  int b = row >> 10;
  float Mrv = Mr[row], s1r = S1r[row], s2r = S2r[row];
  float ads = add_src[row];
  float itt = itau[NB + b], its = itau[b];
  int t = threadIdx.x << 2;
  size_t off = (size_t)row*SQ + t;
  float4 x4  = *(const float4*)(scores + off);
  int bt = b*SQ + t;
  float4 at4 = *(const float4*)(add_tgt + bt);
  float4 mc4 = *(const float4*)(Mc  + bt);
  float4 c14 = *(const float4*)(S1c + bt);
  float4 c24 = *(const float4*)(S2c + bt);
  const float* xp  = (const float*)&x4;
  const float* atp = (const float*)&at4;
  const float* mcp = (const float*)&mc4;
  const float* c1p = (const float*)&c14;
  const float* c2p = (const float*)&c24;
  float o0[4], o1[4];
  #pragma unroll
  for (int j = 0; j < 4; ++j){
    float x  = xp[j];
    float xs = x + atp[j];
    float ps = __expf(xs - Mrv) / s1r;
    float qs = __expf((xs - Mrv)*itt) / s2r;
    float xt = x + ads;
    float pt = __expf(xt - mcp[j]) / c1p[j];
    float qt = __expf((xt - mcp[j])*its) / c2p[j];
    o0[j] = (ps > 1e-3f && pt > 1e-3f) ? 1.0f : 0.0f;
    o1[j] = 2.0f*qs*qt / (qs + qt + 1e-9f);
  }
  *(float4*)(out0 + off) = make_float4(o0[0],o0[1],o0[2],o0[3]);
  *(float4*)(out1 + off) = make_float4(o1[0],o1[1],o1[2],o1[3]);
}

extern "C" void kernel_launch(void* const* d_in, const int* in_sizes, int n_in,
                              void* d_out, int out_size, void* d_ws, size_t ws_size,
                              hipStream_t stream){
  const float* hsrc = (const float*)d_in[0];
  const float* htgt = (const float*)d_in[1];
  const int*   isrc = (const int*)d_in[2];
  const int*   itgt = (const int*)d_in[3];

  float* out0 = (float*)d_out;
  float* out1 = out0 + (size_t)NB*SQ*SQ;
  float* W = (float*)d_ws;

  const size_t NSQ2 = (size_t)NB*SQ*SQ;              // 16,777,216
  const size_t need_fast = (NSQ2 + 16384*2 + 32 + 6*NB*SQ + 2*(size_t)NB*16*3*SQ) * 4;

  if (ws_size >= need_fast){
    float* scores  = W;                         // 16M floats
    float* add_src = W + NSQ2;
    float* add_tgt = add_src + NB*SQ;
    float* itau    = add_tgt + NB*SQ;
    float* Mr      = itau + 32;
    float* S1r     = Mr  + NB*SQ;
    float* S2r     = S1r + NB*SQ;
    float* Mc      = S2r + NB*SQ;
    float* S1c     = Mc  + NB*SQ;
    float* S2c     = S1c + NB*SQ;
    float* rpart   = S2c + NB*SQ;               // NB*16*3*SQ = 786,432 floats
    float* cpart   = rpart + (size_t)NB*16*3*SQ;

    prep_kernel<<<NB, 256, 0, stream>>>(isrc, itgt, add_src, add_tgt, itau);
    gemm_fsplit<<<1024, 256, 0, stream>>>(hsrc, htgt, scores, add_src, add_tgt, itau,
                                          rpart, cpart);
    merge_stats<<<dim3(NB*SQ/256, 2), 256, 0, stream>>>(rpart, cpart, itau,
                                                        Mr, S1r, S2r, Mc, S1c, S2c);
    finalize<<<NB*SQ, 256, 0, stream>>>(scores, add_src, add_tgt, itau,
                                        Mr, S1r, S2r, Mc, S1c, S2c, out0, out1);
  } else {
    // fallback: fp32 GEMM path, scores staged in out1 (finalize overwrites in place)
    float* scores  = out1;
    float* add_src = W;
    float* add_tgt = W + 16384;
    float* itau    = W + 32768;
    float* Mr      = W + 32800;
    float* S1r     = Mr  + NB*SQ;
    float* S2r     = S1r + NB*SQ;
    float* Mc      = S2r + NB*SQ;
    float* S1c     = Mc  + NB*SQ;
    float* S2c     = S1c + NB*SQ;
    float* part    = S2c + NB*SQ;

    prep_kernel<<<NB, 256, 0, stream>>>(isrc, itgt, add_src, add_tgt, itau);
    gemm_nt<<<dim3(8, 8, NB), 256, 0, stream>>>(hsrc, htgt, scores);
    stats_pass<<<NB*NCH, 256, 0, stream>>>(scores, add_src, add_tgt, itau, Mr, S1r, S2r, part);
    col_merge<<<NB*SQ/256, 256, 0, stream>>>(part, itau, Mc, S1c, S2c);
    finalize<<<NB*SQ, 256, 0, stream>>>(scores, add_src, add_tgt, itau,
                                        Mr, S1r, S2r, Mc, S1c, S2c, out0, out1);
  }
}